// Round 7
// baseline (316.158 us; speedup 1.0000x reference)
//
#include <hip/hip_runtime.h>
#include <math.h>

#define BB 32
#define CC 768
#define HWN 1024
#define DD 384
#define KK 64
#define EPSI 20.0f            // 1/eps
#define NORMC (-6.9920964f)   // -log(1088)
#define NITERS 10

typedef __bf16 bf16;
typedef bf16 bf16x8 __attribute__((ext_vector_type(8)));
typedef bf16 bf16x4 __attribute__((ext_vector_type(4)));
typedef float f32x4 __attribute__((ext_vector_type(4)));
typedef _Float16 f16;
typedef f16 f16x2 __attribute__((ext_vector_type(2)));
typedef f16 f16x4 __attribute__((ext_vector_type(4)));

__device__ __forceinline__ float wave_sum(float v){
  #pragma unroll
  for (int off = 32; off; off >>= 1) v += __shfl_xor(v, off, 64);
  return v;
}
__device__ __forceinline__ float wave_max(float v){
  #pragma unroll
  for (int off = 32; off; off >>= 1) v = fmaxf(v, __shfl_xor(v, off, 64));
  return v;
}

__device__ __forceinline__ void async16(const bf16* g, bf16* l){
  __builtin_amdgcn_global_load_lds((const __attribute__((address_space(1))) unsigned int*)g,
                                   (__attribute__((address_space(3))) unsigned int*)l,
                                   16, 0, 0);
}

// ---------------- K0: normalize codebook rows v[64][384] -> clusb (bf16) ------------
__global__ __launch_bounds__(256) void k0_clusters(const float* __restrict__ vin,
                                                   bf16* __restrict__ clusb){
  int w = threadIdx.x >> 6, l = threadIdx.x & 63;
  int k = blockIdx.x * 4 + w;               // 16 blocks * 4 waves = 64 rows
  float s = 0.f;
  #pragma unroll
  for (int i = 0; i < 6; i++){ float x = vin[k*DD + l + 64*i]; s += x*x; }
  s = wave_sum(s);
  float scale = 1.f / fmaxf(sqrtf(s), 1e-12f);
  #pragma unroll
  for (int i = 0; i < 6; i++) clusb[k*DD + l + 64*i] = (bf16)(vin[k*DD + l + 64*i] * scale);
}

// ---------------- KW: convert conv_w fp32[384][768] -> bf16 ----------------
__global__ __launch_bounds__(256) void k_wconv(const float* __restrict__ w,
                                               bf16* __restrict__ wb){
  int i = (blockIdx.x * 256 + threadIdx.x) * 4;
  float4 v = *(const float4*)&w[i];
  bf16x4 o;
  o[0] = (bf16)v.x; o[1] = (bf16)v.y; o[2] = (bf16)v.z; o[3] = (bf16)v.w;
  *(bf16x4*)&wb[i] = o;
}

// ---------------- K1: fused GEMM front-end (v4: W direct-to-register).
// xp[b][n][m] = sum_c X[b][c][n]*W[m][c] + bias[m]; rn fused; xnb = bf16(xp*rn).
// Tile 64n x 384m, grid (16 x 32) = 512 blocks (R5 geometry, measured best).
// Change vs R5: W is NOT staged through LDS. Each wave loads its 6 fragments
// (16 B contiguous per lane) straight from global (L2-resident, 0.6 MB) into
// registers. This removes the per-step block-wide `s_waitcnt vmcnt(0)` drain
// before barrier B (the m97-class stall) — W-load latency becomes per-wave and
// TLP-hidden. Barriers now only order the 8 KB X-transpose LDS (lgkmcnt).
// X staging (unchanged, verified): Xf[64][32] fp32, float4-block XOR swizzle
//   phys(c,n) = (((c>>2) ^ ((n>>3)&7))<<2) | (c&3); addr = n*32 + phys.
//   writes 2-way (free), b128 reads 8 groups x 8 lanes = hw minimum.
__global__ __launch_bounds__(512, 4) void k_gemm(const bf16* __restrict__ Wb,
                                                 const float* __restrict__ X,
                                                 const float* __restrict__ bias,
                                                 float* __restrict__ xp,
                                                 bf16* __restrict__ xnb){
  __shared__ float Xf[64 * 32];       // 8 KB, swizzled
  __shared__ float part[4][64];       // per-wm row sumsq partials
  __shared__ float rn_l[64];
  int b  = blockIdx.y;
  int n0 = blockIdx.x * 64;
  int t = threadIdx.x, wv = t >> 6, l = t & 63;
  int l15 = l & 15, quad = l >> 4;
  int wn = wv >> 2, wm = wv & 3;
  const float* Xg = X + (size_t)b * CC * HWN;

  // W fragment base: row = wm*96 + j*16 + l15, col = c0 + quad*8 (16B contiguous)
  const bf16* gWf = Wb + (size_t)(wm*96 + l15) * CC + quad*8;

  // X staging: cs = t>>4 (0..31 c-rows), n4 = (t&15)*4
  int cs = t >> 4, n4 = (t & 15) * 4;
  const float* gX = Xg + n0 + n4;
  int pw = (t & 15) >> 1;                                   // (n>>3)&7 for n4..n4+3
  int physw = ((((cs >> 2) ^ pw) & 7) << 2) | (cs & 3);
  float* xw = &Xf[n4 * 32 + physw];

  f32x4 acc[2][6];
  const f32x4 zero = {0.f, 0.f, 0.f, 0.f};
  #pragma unroll
  for (int i = 0; i < 2; i++)
    #pragma unroll
    for (int j = 0; j < 6; j++) acc[i][j] = zero;

  float4 xv = *(const float4*)(gX + (size_t)cs * HWN);      // prologue: step 0

  for (int c0 = 0; c0 < CC; c0 += 32){
    __syncthreads();                                        // A: prev reads done
    xw[0] = xv.x; xw[32] = xv.y; xw[64] = xv.z; xw[96] = xv.w;
    __syncthreads();                                        // B: lgkm drain only
    if (c0 + 32 < CC)
      xv = *(const float4*)(gX + (size_t)(c0 + 32 + cs) * HWN);  // T14 prefetch

    bf16x8 xf[2], wf[6];
    #pragma unroll
    for (int j = 0; j < 6; j++)
      wf[j] = *(const bf16x8*)&gWf[(size_t)(j*16) * CC + c0];
    #pragma unroll
    for (int i = 0; i < 2; i++){
      int nloc = wn*32 + i*16 + l15;
      int p = (nloc >> 3) & 7;
      const float4 f0 = *(const float4*)&Xf[nloc*32 + (((2*quad + 0) ^ p) << 2)];
      const float4 f1 = *(const float4*)&Xf[nloc*32 + (((2*quad + 1) ^ p) << 2)];
      bf16x8 c8;
      c8[0] = (bf16)f0.x; c8[1] = (bf16)f0.y; c8[2] = (bf16)f0.z; c8[3] = (bf16)f0.w;
      c8[4] = (bf16)f1.x; c8[5] = (bf16)f1.y; c8[6] = (bf16)f1.z; c8[7] = (bf16)f1.w;
      xf[i] = c8;
    }
    #pragma unroll
    for (int i = 0; i < 2; i++)
      #pragma unroll
      for (int j = 0; j < 6; j++)
        acc[i][j] = __builtin_amdgcn_mfma_f32_16x16x32_bf16(xf[i], wf[j], acc[i][j], 0, 0, 0);
  }

  float bb[6];
  #pragma unroll
  for (int j = 0; j < 6; j++) bb[j] = bias[wm*96 + j*16 + l15];

  // ---- rnorm: per-row sumsq (j-sum, l15-reduce, cross-wm via LDS)
  #pragma unroll
  for (int i = 0; i < 2; i++){
    #pragma unroll
    for (int r = 0; r < 4; r++){
      float s = 0.f;
      #pragma unroll
      for (int j = 0; j < 6; j++){ float v = acc[i][j][r] + bb[j]; s = fmaf(v, v, s); }
      s += __shfl_xor(s, 1, 64); s += __shfl_xor(s, 2, 64);
      s += __shfl_xor(s, 4, 64); s += __shfl_xor(s, 8, 64);
      if (l15 == 0) part[wm][wn*32 + i*16 + quad*4 + r] = s;
    }
  }
  __syncthreads();
  if (t < 64){
    float tot = part[0][t] + part[1][t] + part[2][t] + part[3][t];
    rn_l[t] = 1.f / fmaxf(sqrtf(tot), 1e-12f);
  }
  __syncthreads();

  // ---- write xp fp32 + xnb bf16
  #pragma unroll
  for (int i = 0; i < 2; i++){
    #pragma unroll
    for (int r = 0; r < 4; r++){
      int nloc = wn*32 + i*16 + quad*4 + r;
      float rv = rn_l[nloc];
      float* orow = xp  + ((size_t)b * HWN + n0 + nloc) * DD;
      bf16*  xrow = xnb + ((size_t)b * HWN + n0 + nloc) * DD;
      #pragma unroll
      for (int j = 0; j < 6; j++){
        int m = wm*96 + j*16 + l15;
        float val = acc[i][j][r] + bb[j];
        orow[m] = val;
        xrow[m] = (bf16)(val * rv);
      }
    }
  }
}

// ---------------- KXPT2: bf16 transpose  XpT[b][d][n] = xnb[b][n][d] ----------------
__global__ __launch_bounds__(256) void k_xpt2(const bf16* __restrict__ xnb,
                                              bf16* __restrict__ xpt){
  __shared__ bf16 S[64][72];   // pad 8 bf16 (row 144B)
  int b  = blockIdx.z;
  int d0 = blockIdx.y * 64;
  int n0 = blockIdx.x * 64;
  const bf16* src = xnb + ((size_t)b * HWN + n0) * DD + d0;
  int t = threadIdx.x;
  int r = t >> 3, c8 = (t & 7) * 8;
  #pragma unroll
  for (int it = 0; it < 2; it++){
    bf16x8 v = *(const bf16x8*)&src[(size_t)(r + it*32) * DD + c8];
    *(bf16x8*)&S[r + it*32][c8] = v;
  }
  __syncthreads();
  int d = t >> 2, c0 = (t & 3) * 16;
  bf16* orow = xpt + ((size_t)b * DD + d0 + d) * HWN + n0 + c0;
  bf16x8 o0, o1;
  #pragma unroll
  for (int jj = 0; jj < 8; jj++) o0[jj] = S[c0 + jj][d];
  #pragma unroll
  for (int jj = 0; jj < 8; jj++) o1[jj] = S[c0 + 8 + jj][d];
  *(bf16x8*)&orow[0] = o0;
  *(bf16x8*)&orow[8] = o1;
}

// ---------------- K3 (MFMA): Z[b][k][n] = (clusb[k][:] . xnb[n][:]) * EPSI ----------
__global__ __launch_bounds__(256) void k3_scores(const bf16* __restrict__ clusb,
                                                 const bf16* __restrict__ xnb,
                                                 float* __restrict__ Z){
  __shared__ bf16 Al[64][4][8];    // 4 KB  clusters slab
  __shared__ bf16 Bl[128][4][8];   // 8 KB  xn slab
  int b = blockIdx.y, n0 = blockIdx.x * 128;
  const bf16* Xb = xnb + (size_t)b * HWN * DD;
  int t = threadIdx.x, wv = t >> 6, l = t & 63;
  int l15 = l & 15, quad = l >> 4;

  int rbase = wv*16 + (l >> 2);
  int kq8   = (l & 3) * 8;
  const bf16* gA = clusb + (size_t)rbase * DD + kq8;
  const bf16* gB = Xb + (size_t)(n0 + rbase) * DD + kq8;
  bf16* lA = &Al[0][0][0] + wv * 512;
  bf16* lB = &Bl[0][0][0] + wv * 512;

  f32x4 acc[4][2];
  const f32x4 zero = {0.f, 0.f, 0.f, 0.f};
  #pragma unroll
  for (int i = 0; i < 4; i++){ acc[i][0] = zero; acc[i][1] = zero; }

  for (int d0 = 0; d0 < DD; d0 += 32){
    async16(gA + d0, lA);
    async16(gB + d0,                 lB);
    async16(gB + d0 + (size_t)64*DD, lB + 2048);
    __syncthreads();
    bf16x8 af[4], bf[2];
    #pragma unroll
    for (int i = 0; i < 4; i++)
      af[i] = *(const bf16x8*)&Al[i*16 + l15][quad][0];
    #pragma unroll
    for (int j = 0; j < 2; j++)
      bf[j] = *(const bf16x8*)&Bl[wv*32 + j*16 + l15][quad][0];
    #pragma unroll
    for (int i = 0; i < 4; i++)
      #pragma unroll
      for (int j = 0; j < 2; j++)
        acc[i][j] = __builtin_amdgcn_mfma_f32_16x16x32_bf16(af[i], bf[j], acc[i][j], 0, 0, 0);
    __syncthreads();
  }
  #pragma unroll
  for (int i = 0; i < 4; i++){
    #pragma unroll
    for (int j = 0; j < 2; j++){
      int n = n0 + wv*32 + j*16 + l15;
      #pragma unroll
      for (int r = 0; r < 4; r++){
        int k = i*16 + quad*4 + r;
        Z[((size_t)b*KK + k)*HWN + n] = acc[i][j][r] * EPSI;
      }
    }
  }
}

// ---------------- K4: Sinkhorn, one 1024-thr block per batch, E=exp(Z-rmax) in f16 LDS
// u[r] = NORMC - rmax[r] - log(sum_n E[r][n]*ev[n]);  eu[r] = exp(NORMC)/sum  (exact)
// v[c] = NORMC - log(sum_m E[m][c]*eu[m]);            ev[c] = exp(v[c])
// NOTE: v reaches ~+12 (asymmetric marginals 64 vs 1024) -> ev MUST be fp32.
// E in (0,1] is always f16-safe. ~145 KB LDS (gfx950: 160 KB/CU).
__global__ __launch_bounds__(1024) void k4_sinkhorn(const float* __restrict__ Z,
                                                    float* __restrict__ U,
                                                    float* __restrict__ V){
  __shared__ f16  E[64][1024];    // 128 KB
  __shared__ float evf[1024];     // exp(v), fp32 (overflow-safe)
  __shared__ float eu[64];
  __shared__ float rmax[64];
  __shared__ float u_l[64];
  __shared__ float v_l[1024];
  __shared__ float sp[2][1024];   // v-phase partials per column (two row-halves)
  int b = blockIdx.x;
  const float* Zb = Z + (size_t)b * KK * HWN;
  int t = threadIdx.x, w = t >> 6, l = t & 63;

  #pragma unroll
  for (int rr = 0; rr < 4; rr++){
    int r = w*4 + rr;
    float4 z[4];
    float mx = -INFINITY;
    #pragma unroll
    for (int j = 0; j < 4; j++){
      z[j] = *(const float4*)&Zb[(size_t)r*HWN + 4*l + 256*j];
      mx = fmaxf(mx, fmaxf(fmaxf(z[j].x, z[j].y), fmaxf(z[j].z, z[j].w)));
    }
    mx = wave_max(mx);
    if (l == 0) rmax[r] = mx;
    #pragma unroll
    for (int j = 0; j < 4; j++){
      f16x4 e4;
      e4[0] = (f16)__expf(z[j].x - mx); e4[1] = (f16)__expf(z[j].y - mx);
      e4[2] = (f16)__expf(z[j].z - mx); e4[3] = (f16)__expf(z[j].w - mx);
      *(f16x4*)&E[r][4*l + 256*j] = e4;
    }
  }
  evf[t] = 1.f;
  v_l[t] = 0.f;
  __syncthreads();

  for (int it = 0; it < NITERS; it++){
    float evx[16];
    #pragma unroll
    for (int j = 0; j < 8; j++){
      float2 e2 = *(const float2*)&evf[2*(l + 64*j)];
      evx[2*j] = e2.x; evx[2*j+1] = e2.y;
    }
    float us[4];
    #pragma unroll
    for (int rr = 0; rr < 4; rr++){
      int r = w*4 + rr;
      float s = 0.f;
      #pragma unroll
      for (int j = 0; j < 8; j++){
        f16x2 e2 = *(const f16x2*)&E[r][2*(l + 64*j)];
        s = fmaf((float)e2[0], evx[2*j],   s);
        s = fmaf((float)e2[1], evx[2*j+1], s);
      }
      us[rr] = wave_sum(s);
    }
    if (l == 0){
      #pragma unroll
      for (int rr = 0; rr < 4; rr++){
        int r = w*4 + rr;
        u_l[r] = NORMC - rmax[r] - __logf(us[rr]);
        eu[r]  = __expf(NORMC) / us[rr];
      }
    }
    __syncthreads();
    {
      int p = t & 511, h = t >> 9;
      float sx = 0.f, sy = 0.f;
      #pragma unroll
      for (int mq = 0; mq < 8; mq++){
        float4 eu4 = *(const float4*)&eu[h*32 + mq*4];
        const float euv[4] = {eu4.x, eu4.y, eu4.z, eu4.w};
        #pragma unroll
        for (int i = 0; i < 4; i++){
          f16x2 e2 = *(const f16x2*)&E[h*32 + mq*4 + i][2*p];
          sx = fmaf((float)e2[0], euv[i], sx);
          sy = fmaf((float)e2[1], euv[i], sy);
        }
      }
      float2 o; o.x = sx; o.y = sy;
      *(float2*)&sp[h][2*p] = o;
    }
    __syncthreads();
    if (t < 512){
      int p = t;
      float2 a = *(const float2*)&sp[0][2*p];
      float2 c = *(const float2*)&sp[1][2*p];
      float vx = NORMC - __logf(a.x + c.x);
      float vy = NORMC - __logf(a.y + c.y);
      v_l[2*p]   = vx;
      v_l[2*p+1] = vy;
      float2 ee; ee.x = __expf(vx); ee.y = __expf(vy);
      *(float2*)&evf[2*p] = ee;
    }
    __syncthreads();
  }
  V[b*HWN + t] = v_l[t];
  if (t < 64) U[b*KK + t] = u_l[t];
}

// ---------------- K5 (MFMA, split-K over n): out[b][k][d] += sum_n E'[k][n]*XpT[d][n]
// E'[k][n] = exp(Z+u+v-NORMC) in bf16 (rn already folded into XpT).
// Grid (8 chunks x 32 b) = 256 blocks; 4 n-steps of 32 per block; atomic partials.
__global__ __launch_bounds__(256) void k5_mfma(const float* __restrict__ Z,
                                               const float* __restrict__ U,
                                               const float* __restrict__ V,
                                               const bf16* __restrict__ XpT,
                                               float* __restrict__ out){
  __shared__ bf16 El[64][40];     // 5 KB   [k][n-step]
  __shared__ bf16 Xl[384][40];    // 30 KB  [d][n-step]
  int b  = blockIdx.y;
  int nsb = blockIdx.x * 128;     // n-chunk base
  const float* Zb = Z + (size_t)b * KK * HWN;
  const bf16*  Xb = XpT + (size_t)b * DD * HWN;
  const float* Vb = V + (size_t)b * HWN;
  int t = threadIdx.x, wv = t >> 6, l = t & 63;
  int l15 = l & 15, quad = l >> 4;
  int er = t >> 2, ec0 = (t & 3) * 8;
  float ur = U[b*KK + er];

  f32x4 acc[4][6];
  const f32x4 zero = {0.f, 0.f, 0.f, 0.f};
  #pragma unroll
  for (int i = 0; i < 4; i++)
    #pragma unroll
    for (int j = 0; j < 6; j++) acc[i][j] = zero;

  for (int st = 0; st < 4; st++){
    int n0 = nsb + st*32;
    {
      float4 z0 = *(const float4*)&Zb[(size_t)er*HWN + n0 + ec0];
      float4 z1 = *(const float4*)&Zb[(size_t)er*HWN + n0 + ec0 + 4];
      float4 v0 = *(const float4*)&Vb[n0 + ec0];
      float4 v1 = *(const float4*)&Vb[n0 + ec0 + 4];
      bf16x8 e;
      e[0] = (bf16)__expf(z0.x + ur + v0.x - NORMC);
      e[1] = (bf16)__expf(z0.y + ur + v0.y - NORMC);
      e[2] = (bf16)__expf(z0.z + ur + v0.z - NORMC);
      e[3] = (bf16)__expf(z0.w + ur + v0.w - NORMC);
      e[4] = (bf16)__expf(z1.x + ur + v1.x - NORMC);
      e[5] = (bf16)__expf(z1.y + ur + v1.y - NORMC);
      e[6] = (bf16)__expf(z1.z + ur + v1.z - NORMC);
      e[7] = (bf16)__expf(z1.w + ur + v1.w - NORMC);
      *(bf16x8*)&El[er][ec0] = e;
    }
    #pragma unroll
    for (int ii = 0; ii < 6; ii++){
      int chunk = t + 256*ii;
      int d = chunk >> 2, cb = (chunk & 3) * 8;
      bf16x8 xv = *(const bf16x8*)&Xb[(size_t)d*HWN + n0 + cb];
      *(bf16x8*)&Xl[d][cb] = xv;
    }
    __syncthreads();
    bf16x8 af[4], bfr[6];
    #pragma unroll
    for (int i = 0; i < 4; i++)
      af[i] = *(const bf16x8*)&El[i*16 + l15][quad*8];
    #pragma unroll
    for (int j = 0; j < 6; j++)
      bfr[j] = *(const bf16x8*)&Xl[wv*96 + j*16 + l15][quad*8];
    #pragma unroll
    for (int i = 0; i < 4; i++)
      #pragma unroll
      for (int j = 0; j < 6; j++)
        acc[i][j] = __builtin_amdgcn_mfma_f32_16x16x32_bf16(af[i], bfr[j], acc[i][j], 0, 0, 0);
    __syncthreads();
  }

  float* ob = out + (size_t)b * KK * DD;
  #pragma unroll
  for (int i = 0; i < 4; i++){
    int kbase = i*16 + quad*4;
    #pragma unroll
    for (int j = 0; j < 6; j++){
      int d = wv*96 + j*16 + l15;
      #pragma unroll
      for (int r = 0; r < 4; r++)
        unsafeAtomicAdd(&ob[(size_t)(kbase + r)*DD + d], acc[i][j][r]);
    }
  }
}

extern "C" void kernel_launch(void* const* d_in, const int* in_sizes, int n_in,
                              void* d_out, int out_size, void* d_ws, size_t ws_size,
                              hipStream_t stream) {
  const float* x      = (const float*)d_in[0];   // [32,768,32,32]
  const float* conv_w = (const float*)d_in[1];   // [384,768]
  const float* conv_b = (const float*)d_in[2];   // [384]
  const float* vcode  = (const float*)d_in[3];   // [64,384]
  float* out = (float*)d_out;
  float* vt_out = out;                 // [32,64,384]  = 786432
  float* xp_out = out + 786432;        // [32,1024,384]

  bf16* xnb   = (bf16*)d_ws;                         // 12,582,912 bf16 (25.2 MB)
  bf16* XpT   = xnb + (size_t)BB * HWN * DD;         // 12,582,912 bf16 (25.2 MB)
  bf16* Wb    = XpT + (size_t)BB * HWN * DD;         // 294,912 bf16
  bf16* clusb = Wb + (size_t)DD * CC;                // 24,576 bf16
  float* Zbuf = (float*)(clusb + 24576);             // 2,097,152 f32
  float* Ubuf = Zbuf + 2097152;                      // 2,048
  float* Vbuf = Ubuf + 2048;                         // 32,768

  hipMemsetAsync(vt_out, 0, (size_t)786432 * sizeof(float), stream);
  k0_clusters<<<16, 256, 0, stream>>>(vcode, clusb);
  k_wconv<<<288, 256, 0, stream>>>(conv_w, Wb);
  k_gemm<<<dim3(16, 32), 512, 0, stream>>>(Wb, x, conv_b, xp_out, xnb);
  k_xpt2<<<dim3(16, 6, 32), 256, 0, stream>>>(xnb, XpT);
  k3_scores<<<dim3(8, 32), 256, 0, stream>>>(clusb, xnb, Zbuf);
  k4_sinkhorn<<<32, 1024, 0, stream>>>(Zbuf, Ubuf, Vbuf);
  k5_mfma<<<dim3(8, 32), 256, 0, stream>>>(Zbuf, Ubuf, Vbuf, XpT, vt_out);
}

// Round 8
// 276.660 us; speedup vs baseline: 1.1428x; 1.1428x over previous
//
#include <hip/hip_runtime.h>
#include <math.h>

#define BB 32
#define CC 768
#define HWN 1024
#define DD 384
#define KK 64
#define EPSI 20.0f            // 1/eps
#define NORMC (-6.9920964f)   // -log(1088)
#define NITERS 10

typedef __bf16 bf16;
typedef bf16 bf16x8 __attribute__((ext_vector_type(8)));
typedef bf16 bf16x4 __attribute__((ext_vector_type(4)));
typedef float f32x4 __attribute__((ext_vector_type(4)));
typedef _Float16 f16;
typedef f16 f16x2 __attribute__((ext_vector_type(2)));
typedef f16 f16x4 __attribute__((ext_vector_type(4)));

__device__ __forceinline__ float wave_sum(float v){
  #pragma unroll
  for (int off = 32; off; off >>= 1) v += __shfl_xor(v, off, 64);
  return v;
}
__device__ __forceinline__ float wave_max(float v){
  #pragma unroll
  for (int off = 32; off; off >>= 1) v = fmaxf(v, __shfl_xor(v, off, 64));
  return v;
}

__device__ __forceinline__ void async16(const bf16* g, bf16* l){
  __builtin_amdgcn_global_load_lds((const __attribute__((address_space(1))) unsigned int*)g,
                                   (__attribute__((address_space(3))) unsigned int*)l,
                                   16, 0, 0);
}

// ---------------- K0: normalize codebook rows v[64][384] -> clusb (bf16) ------------
__global__ __launch_bounds__(256) void k0_clusters(const float* __restrict__ vin,
                                                   bf16* __restrict__ clusb){
  int w = threadIdx.x >> 6, l = threadIdx.x & 63;
  int k = blockIdx.x * 4 + w;               // 16 blocks * 4 waves = 64 rows
  float s = 0.f;
  #pragma unroll
  for (int i = 0; i < 6; i++){ float x = vin[k*DD + l + 64*i]; s += x*x; }
  s = wave_sum(s);
  float scale = 1.f / fmaxf(sqrtf(s), 1e-12f);
  #pragma unroll
  for (int i = 0; i < 6; i++) clusb[k*DD + l + 64*i] = (bf16)(vin[k*DD + l + 64*i] * scale);
}

// ---------------- KW: convert conv_w fp32[384][768] -> bf16 ----------------
__global__ __launch_bounds__(256) void k_wconv(const float* __restrict__ w,
                                               bf16* __restrict__ wb){
  int i = (blockIdx.x * 256 + threadIdx.x) * 4;
  float4 v = *(const float4*)&w[i];
  bf16x4 o;
  o[0] = (bf16)v.x; o[1] = (bf16)v.y; o[2] = (bf16)v.z; o[3] = (bf16)v.w;
  *(bf16x4*)&wb[i] = o;
}

// ---------------- K1: fused GEMM front-end (v5: R5 + W double-buffer + counted waits).
// xp[b][n][m] = sum_c X[b][c][n]*W[m][c] + bias[m]; rn fused; xnb = bf16(xp*rn).
// Tile 64n x 384m, grid (16 x 32) = 512 blocks (R5 geometry, measured best 61 us).
// Change vs R5: Wl is double-buffered and barriers are raw s_barrier with explicit
// lgkmcnt(0)-only waits. The X prefetch reg xv (issued AFTER last step's W loads)
// is consumed by the ds_write at step top -> compiler's vmcnt(0) there drains the
// CURRENT W buffer one full iteration after issue (latency hidden); the NEXT W
// buffer (issued after that point) stays in flight across both barriers (T3/T4).
// X staging (unchanged, verified): Xf[64][32] fp32, float4-block XOR swizzle
//   phys(c,n) = (((c>>2) ^ ((n>>3)&7))<<2) | (c&3); addr = n*32 + phys.
__global__ __launch_bounds__(512) void k_gemm(const bf16* __restrict__ Wb,
                                              const float* __restrict__ X,
                                              const float* __restrict__ bias,
                                              float* __restrict__ xp,
                                              bf16* __restrict__ xnb){
  __shared__ bf16  Wl[2][384][4][8];  // 48 KB, double-buffered
  __shared__ float Xf[64 * 32];       // 8 KB, swizzled
  __shared__ float part[4][64];       // per-wm row sumsq partials
  __shared__ float rn_l[64];
  int b  = blockIdx.y;
  int n0 = blockIdx.x * 64;
  int t = threadIdx.x, wv = t >> 6, l = t & 63;
  int l15 = l & 15, quad = l >> 4;
  int wn = wv >> 2, wm = wv & 3;
  const float* Xg = X + (size_t)b * CC * HWN;

  // W staging: chunk = t + 512*ii -> row = t>>2 + 128*ii, kq = t&3 (lane-linear LDS)
  const bf16* gW = Wb + (size_t)(t >> 2) * CC + (t & 3) * 8;
  bf16* lW0 = &Wl[0][0][0][0] + wv * 512;
  bf16* lW1 = &Wl[1][0][0][0] + wv * 512;

  // X staging: cs = t>>4 (0..31 c-rows), n4 = (t&15)*4
  int cs = t >> 4, n4 = (t & 15) * 4;
  const float* gX = Xg + n0 + n4;
  int pw = (t & 15) >> 1;                                   // (n>>3)&7 for n4..n4+3
  int physw = ((((cs >> 2) ^ pw) & 7) << 2) | (cs & 3);
  float* xw = &Xf[n4 * 32 + physw];

  f32x4 acc[2][6];
  const f32x4 zero = {0.f, 0.f, 0.f, 0.f};
  #pragma unroll
  for (int i = 0; i < 2; i++)
    #pragma unroll
    for (int j = 0; j < 6; j++) acc[i][j] = zero;

  // prologue: W(0) -> buf0, X(0) -> reg
  async16(gW,                  lW0);
  async16(gW + (size_t)128*CC, lW0 + 4096);
  async16(gW + (size_t)256*CC, lW0 + 8192);
  float4 xv = *(const float4*)(gX + (size_t)cs * HWN);

  for (int c0 = 0; c0 < CC; c0 += 32){
    int cur = (c0 >> 5) & 1;
    bf16* lWn = cur ? lW0 : lW1;

    asm volatile("s_waitcnt lgkmcnt(0)" ::: "memory");
    __builtin_amdgcn_s_barrier();                           // A: prev reads done
    asm volatile("" ::: "memory");
    // X store — compiler emits vmcnt(0) for xv here, which also drains this
    // wave's W(cur) loads (issued before xv last iteration).
    xw[0] = xv.x; xw[32] = xv.y; xw[64] = xv.z; xw[96] = xv.w;
    if (c0 + 32 < CC){
      async16(gW + c0 + 32,                  lWn);
      async16(gW + c0 + 32 + (size_t)128*CC, lWn + 4096);
      async16(gW + c0 + 32 + (size_t)256*CC, lWn + 8192);
    }
    asm volatile("s_waitcnt lgkmcnt(0)" ::: "memory");
    __builtin_amdgcn_s_barrier();                           // B: X writes + W(cur) visible
    asm volatile("" ::: "memory");
    if (c0 + 32 < CC)
      xv = *(const float4*)(gX + (size_t)(c0 + 32 + cs) * HWN);  // T14 prefetch

    bf16x8 xf[2], wf[6];
    #pragma unroll
    for (int j = 0; j < 6; j++)
      wf[j] = *(const bf16x8*)&Wl[cur][wm*96 + j*16 + l15][quad][0];
    #pragma unroll
    for (int i = 0; i < 2; i++){
      int nloc = wn*32 + i*16 + l15;
      int p = (nloc >> 3) & 7;
      const float4 f0 = *(const float4*)&Xf[nloc*32 + (((2*quad + 0) ^ p) << 2)];
      const float4 f1 = *(const float4*)&Xf[nloc*32 + (((2*quad + 1) ^ p) << 2)];
      bf16x8 c8;
      c8[0] = (bf16)f0.x; c8[1] = (bf16)f0.y; c8[2] = (bf16)f0.z; c8[3] = (bf16)f0.w;
      c8[4] = (bf16)f1.x; c8[5] = (bf16)f1.y; c8[6] = (bf16)f1.z; c8[7] = (bf16)f1.w;
      xf[i] = c8;
    }
    #pragma unroll
    for (int i = 0; i < 2; i++)
      #pragma unroll
      for (int j = 0; j < 6; j++)
        acc[i][j] = __builtin_amdgcn_mfma_f32_16x16x32_bf16(xf[i], wf[j], acc[i][j], 0, 0, 0);
  }

  float bb[6];
  #pragma unroll
  for (int j = 0; j < 6; j++) bb[j] = bias[wm*96 + j*16 + l15];

  // ---- rnorm: per-row sumsq (j-sum, l15-reduce, cross-wm via LDS)
  #pragma unroll
  for (int i = 0; i < 2; i++){
    #pragma unroll
    for (int r = 0; r < 4; r++){
      float s = 0.f;
      #pragma unroll
      for (int j = 0; j < 6; j++){ float v = acc[i][j][r] + bb[j]; s = fmaf(v, v, s); }
      s += __shfl_xor(s, 1, 64); s += __shfl_xor(s, 2, 64);
      s += __shfl_xor(s, 4, 64); s += __shfl_xor(s, 8, 64);
      if (l15 == 0) part[wm][wn*32 + i*16 + quad*4 + r] = s;
    }
  }
  __syncthreads();
  if (t < 64){
    float tot = part[0][t] + part[1][t] + part[2][t] + part[3][t];
    rn_l[t] = 1.f / fmaxf(sqrtf(tot), 1e-12f);
  }
  __syncthreads();

  // ---- write xp fp32 + xnb bf16
  #pragma unroll
  for (int i = 0; i < 2; i++){
    #pragma unroll
    for (int r = 0; r < 4; r++){
      int nloc = wn*32 + i*16 + quad*4 + r;
      float rv = rn_l[nloc];
      float* orow = xp  + ((size_t)b * HWN + n0 + nloc) * DD;
      bf16*  xrow = xnb + ((size_t)b * HWN + n0 + nloc) * DD;
      #pragma unroll
      for (int j = 0; j < 6; j++){
        int m = wm*96 + j*16 + l15;
        float val = acc[i][j][r] + bb[j];
        orow[m] = val;
        xrow[m] = (bf16)(val * rv);
      }
    }
  }
}

// ---------------- KXPT2: bf16 transpose  XpT[b][d][n] = xnb[b][n][d] ----------------
__global__ __launch_bounds__(256) void k_xpt2(const bf16* __restrict__ xnb,
                                              bf16* __restrict__ xpt){
  __shared__ bf16 S[64][72];   // pad 8 bf16 (row 144B)
  int b  = blockIdx.z;
  int d0 = blockIdx.y * 64;
  int n0 = blockIdx.x * 64;
  const bf16* src = xnb + ((size_t)b * HWN + n0) * DD + d0;
  int t = threadIdx.x;
  int r = t >> 3, c8 = (t & 7) * 8;
  #pragma unroll
  for (int it = 0; it < 2; it++){
    bf16x8 v = *(const bf16x8*)&src[(size_t)(r + it*32) * DD + c8];
    *(bf16x8*)&S[r + it*32][c8] = v;
  }
  __syncthreads();
  int d = t >> 2, c0 = (t & 3) * 16;
  bf16* orow = xpt + ((size_t)b * DD + d0 + d) * HWN + n0 + c0;
  bf16x8 o0, o1;
  #pragma unroll
  for (int jj = 0; jj < 8; jj++) o0[jj] = S[c0 + jj][d];
  #pragma unroll
  for (int jj = 0; jj < 8; jj++) o1[jj] = S[c0 + 8 + jj][d];
  *(bf16x8*)&orow[0] = o0;
  *(bf16x8*)&orow[8] = o1;
}

// ---------------- K3 (MFMA): Z[b][k][n] = (clusb[k][:] . xnb[n][:]) * EPSI ----------
__global__ __launch_bounds__(256) void k3_scores(const bf16* __restrict__ clusb,
                                                 const bf16* __restrict__ xnb,
                                                 float* __restrict__ Z){
  __shared__ bf16 Al[64][4][8];    // 4 KB  clusters slab
  __shared__ bf16 Bl[128][4][8];   // 8 KB  xn slab
  int b = blockIdx.y, n0 = blockIdx.x * 128;
  const bf16* Xb = xnb + (size_t)b * HWN * DD;
  int t = threadIdx.x, wv = t >> 6, l = t & 63;
  int l15 = l & 15, quad = l >> 4;

  int rbase = wv*16 + (l >> 2);
  int kq8   = (l & 3) * 8;
  const bf16* gA = clusb + (size_t)rbase * DD + kq8;
  const bf16* gB = Xb + (size_t)(n0 + rbase) * DD + kq8;
  bf16* lA = &Al[0][0][0] + wv * 512;
  bf16* lB = &Bl[0][0][0] + wv * 512;

  f32x4 acc[4][2];
  const f32x4 zero = {0.f, 0.f, 0.f, 0.f};
  #pragma unroll
  for (int i = 0; i < 4; i++){ acc[i][0] = zero; acc[i][1] = zero; }

  for (int d0 = 0; d0 < DD; d0 += 32){
    async16(gA + d0, lA);
    async16(gB + d0,                 lB);
    async16(gB + d0 + (size_t)64*DD, lB + 2048);
    __syncthreads();
    bf16x8 af[4], bf[2];
    #pragma unroll
    for (int i = 0; i < 4; i++)
      af[i] = *(const bf16x8*)&Al[i*16 + l15][quad][0];
    #pragma unroll
    for (int j = 0; j < 2; j++)
      bf[j] = *(const bf16x8*)&Bl[wv*32 + j*16 + l15][quad][0];
    #pragma unroll
    for (int i = 0; i < 4; i++)
      #pragma unroll
      for (int j = 0; j < 2; j++)
        acc[i][j] = __builtin_amdgcn_mfma_f32_16x16x32_bf16(af[i], bf[j], acc[i][j], 0, 0, 0);
    __syncthreads();
  }
  #pragma unroll
  for (int i = 0; i < 4; i++){
    #pragma unroll
    for (int j = 0; j < 2; j++){
      int n = n0 + wv*32 + j*16 + l15;
      #pragma unroll
      for (int r = 0; r < 4; r++){
        int k = i*16 + quad*4 + r;
        Z[((size_t)b*KK + k)*HWN + n] = acc[i][j][r] * EPSI;
      }
    }
  }
}

// ---------------- K4: Sinkhorn, one 1024-thr block per batch, E=exp(Z-rmax) in f16 LDS
// u[r] = NORMC - rmax[r] - log(sum_n E[r][n]*ev[n]);  eu[r] = exp(NORMC)/sum  (exact)
// v[c] = NORMC - log(sum_m E[m][c]*eu[m]);            ev[c] = exp(v[c])
// NOTE: v reaches ~+12 (asymmetric marginals 64 vs 1024) -> ev MUST be fp32.
// E in (0,1] is always f16-safe. ~145 KB LDS (gfx950: 160 KB/CU).
__global__ __launch_bounds__(1024) void k4_sinkhorn(const float* __restrict__ Z,
                                                    float* __restrict__ U,
                                                    float* __restrict__ V){
  __shared__ f16  E[64][1024];    // 128 KB
  __shared__ float evf[1024];     // exp(v), fp32 (overflow-safe)
  __shared__ float eu[64];
  __shared__ float rmax[64];
  __shared__ float u_l[64];
  __shared__ float v_l[1024];
  __shared__ float sp[2][1024];   // v-phase partials per column (two row-halves)
  int b = blockIdx.x;
  const float* Zb = Z + (size_t)b * KK * HWN;
  int t = threadIdx.x, w = t >> 6, l = t & 63;

  #pragma unroll
  for (int rr = 0; rr < 4; rr++){
    int r = w*4 + rr;
    float4 z[4];
    float mx = -INFINITY;
    #pragma unroll
    for (int j = 0; j < 4; j++){
      z[j] = *(const float4*)&Zb[(size_t)r*HWN + 4*l + 256*j];
      mx = fmaxf(mx, fmaxf(fmaxf(z[j].x, z[j].y), fmaxf(z[j].z, z[j].w)));
    }
    mx = wave_max(mx);
    if (l == 0) rmax[r] = mx;
    #pragma unroll
    for (int j = 0; j < 4; j++){
      f16x4 e4;
      e4[0] = (f16)__expf(z[j].x - mx); e4[1] = (f16)__expf(z[j].y - mx);
      e4[2] = (f16)__expf(z[j].z - mx); e4[3] = (f16)__expf(z[j].w - mx);
      *(f16x4*)&E[r][4*l + 256*j] = e4;
    }
  }
  evf[t] = 1.f;
  v_l[t] = 0.f;
  __syncthreads();

  for (int it = 0; it < NITERS; it++){
    float evx[16];
    #pragma unroll
    for (int j = 0; j < 8; j++){
      float2 e2 = *(const float2*)&evf[2*(l + 64*j)];
      evx[2*j] = e2.x; evx[2*j+1] = e2.y;
    }
    float us[4];
    #pragma unroll
    for (int rr = 0; rr < 4; rr++){
      int r = w*4 + rr;
      float s = 0.f;
      #pragma unroll
      for (int j = 0; j < 8; j++){
        f16x2 e2 = *(const f16x2*)&E[r][2*(l + 64*j)];
        s = fmaf((float)e2[0], evx[2*j],   s);
        s = fmaf((float)e2[1], evx[2*j+1], s);
      }
      us[rr] = wave_sum(s);
    }
    if (l == 0){
      #pragma unroll
      for (int rr = 0; rr < 4; rr++){
        int r = w*4 + rr;
        u_l[r] = NORMC - rmax[r] - __logf(us[rr]);
        eu[r]  = __expf(NORMC) / us[rr];
      }
    }
    __syncthreads();
    {
      int p = t & 511, h = t >> 9;
      float sx = 0.f, sy = 0.f;
      #pragma unroll
      for (int mq = 0; mq < 8; mq++){
        float4 eu4 = *(const float4*)&eu[h*32 + mq*4];
        const float euv[4] = {eu4.x, eu4.y, eu4.z, eu4.w};
        #pragma unroll
        for (int i = 0; i < 4; i++){
          f16x2 e2 = *(const f16x2*)&E[h*32 + mq*4 + i][2*p];
          sx = fmaf((float)e2[0], euv[i], sx);
          sy = fmaf((float)e2[1], euv[i], sy);
        }
      }
      float2 o; o.x = sx; o.y = sy;
      *(float2*)&sp[h][2*p] = o;
    }
    __syncthreads();
    if (t < 512){
      int p = t;
      float2 a = *(const float2*)&sp[0][2*p];
      float2 c = *(const float2*)&sp[1][2*p];
      float vx = NORMC - __logf(a.x + c.x);
      float vy = NORMC - __logf(a.y + c.y);
      v_l[2*p]   = vx;
      v_l[2*p+1] = vy;
      float2 ee; ee.x = __expf(vx); ee.y = __expf(vy);
      *(float2*)&evf[2*p] = ee;
    }
    __syncthreads();
  }
  V[b*HWN + t] = v_l[t];
  if (t < 64) U[b*KK + t] = u_l[t];
}

// ---------------- K5 (MFMA, split-K over n): out[b][k][d] += sum_n E'[k][n]*XpT[d][n]
// E'[k][n] = exp(Z+u+v-NORMC) in bf16 (rn already folded into XpT).
// Grid (8 chunks x 32 b) = 256 blocks; 4 n-steps of 32 per block; atomic partials.
__global__ __launch_bounds__(256) void k5_mfma(const float* __restrict__ Z,
                                               const float* __restrict__ U,
                                               const float* __restrict__ V,
                                               const bf16* __restrict__ XpT,
                                               float* __restrict__ out){
  __shared__ bf16 El[64][40];     // 5 KB   [k][n-step]
  __shared__ bf16 Xl[384][40];    // 30 KB  [d][n-step]
  int b  = blockIdx.y;
  int nsb = blockIdx.x * 128;     // n-chunk base
  const float* Zb = Z + (size_t)b * KK * HWN;
  const bf16*  Xb = XpT + (size_t)b * DD * HWN;
  const float* Vb = V + (size_t)b * HWN;
  int t = threadIdx.x, wv = t >> 6, l = t & 63;
  int l15 = l & 15, quad = l >> 4;
  int er = t >> 2, ec0 = (t & 3) * 8;
  float ur = U[b*KK + er];

  f32x4 acc[4][6];
  const f32x4 zero = {0.f, 0.f, 0.f, 0.f};
  #pragma unroll
  for (int i = 0; i < 4; i++)
    #pragma unroll
    for (int j = 0; j < 6; j++) acc[i][j] = zero;

  for (int st = 0; st < 4; st++){
    int n0 = nsb + st*32;
    {
      float4 z0 = *(const float4*)&Zb[(size_t)er*HWN + n0 + ec0];
      float4 z1 = *(const float4*)&Zb[(size_t)er*HWN + n0 + ec0 + 4];
      float4 v0 = *(const float4*)&Vb[n0 + ec0];
      float4 v1 = *(const float4*)&Vb[n0 + ec0 + 4];
      bf16x8 e;
      e[0] = (bf16)__expf(z0.x + ur + v0.x - NORMC);
      e[1] = (bf16)__expf(z0.y + ur + v0.y - NORMC);
      e[2] = (bf16)__expf(z0.z + ur + v0.z - NORMC);
      e[3] = (bf16)__expf(z0.w + ur + v0.w - NORMC);
      e[4] = (bf16)__expf(z1.x + ur + v1.x - NORMC);
      e[5] = (bf16)__expf(z1.y + ur + v1.y - NORMC);
      e[6] = (bf16)__expf(z1.z + ur + v1.z - NORMC);
      e[7] = (bf16)__expf(z1.w + ur + v1.w - NORMC);
      *(bf16x8*)&El[er][ec0] = e;
    }
    #pragma unroll
    for (int ii = 0; ii < 6; ii++){
      int chunk = t + 256*ii;
      int d = chunk >> 2, cb = (chunk & 3) * 8;
      bf16x8 xv = *(const bf16x8*)&Xb[(size_t)d*HWN + n0 + cb];
      *(bf16x8*)&Xl[d][cb] = xv;
    }
    __syncthreads();
    bf16x8 af[4], bfr[6];
    #pragma unroll
    for (int i = 0; i < 4; i++)
      af[i] = *(const bf16x8*)&El[i*16 + l15][quad*8];
    #pragma unroll
    for (int j = 0; j < 6; j++)
      bfr[j] = *(const bf16x8*)&Xl[wv*96 + j*16 + l15][quad*8];
    #pragma unroll
    for (int i = 0; i < 4; i++)
      #pragma unroll
      for (int j = 0; j < 6; j++)
        acc[i][j] = __builtin_amdgcn_mfma_f32_16x16x32_bf16(af[i], bfr[j], acc[i][j], 0, 0, 0);
    __syncthreads();
  }

  float* ob = out + (size_t)b * KK * DD;
  #pragma unroll
  for (int i = 0; i < 4; i++){
    int kbase = i*16 + quad*4;
    #pragma unroll
    for (int j = 0; j < 6; j++){
      int d = wv*96 + j*16 + l15;
      #pragma unroll
      for (int r = 0; r < 4; r++)
        unsafeAtomicAdd(&ob[(size_t)(kbase + r)*DD + d], acc[i][j][r]);
    }
  }
}

extern "C" void kernel_launch(void* const* d_in, const int* in_sizes, int n_in,
                              void* d_out, int out_size, void* d_ws, size_t ws_size,
                              hipStream_t stream) {
  const float* x      = (const float*)d_in[0];   // [32,768,32,32]
  const float* conv_w = (const float*)d_in[1];   // [384,768]
  const float* conv_b = (const float*)d_in[2];   // [384]
  const float* vcode  = (const float*)d_in[3];   // [64,384]
  float* out = (float*)d_out;
  float* vt_out = out;                 // [32,64,384]  = 786432
  float* xp_out = out + 786432;        // [32,1024,384]

  bf16* xnb   = (bf16*)d_ws;                         // 12,582,912 bf16 (25.2 MB)
  bf16* XpT   = xnb + (size_t)BB * HWN * DD;         // 12,582,912 bf16 (25.2 MB)
  bf16* Wb    = XpT + (size_t)BB * HWN * DD;         // 294,912 bf16
  bf16* clusb = Wb + (size_t)DD * CC;                // 24,576 bf16
  float* Zbuf = (float*)(clusb + 24576);             // 2,097,152 f32
  float* Ubuf = Zbuf + 2097152;                      // 2,048
  float* Vbuf = Ubuf + 2048;                         // 32,768

  hipMemsetAsync(vt_out, 0, (size_t)786432 * sizeof(float), stream);
  k0_clusters<<<16, 256, 0, stream>>>(vcode, clusb);
  k_wconv<<<288, 256, 0, stream>>>(conv_w, Wb);
  k_gemm<<<dim3(16, 32), 512, 0, stream>>>(Wb, x, conv_b, xp_out, xnb);
  k_xpt2<<<dim3(16, 6, 32), 256, 0, stream>>>(xnb, XpT);
  k3_scores<<<dim3(8, 32), 256, 0, stream>>>(clusb, xnb, Zbuf);
  k4_sinkhorn<<<32, 1024, 0, stream>>>(Zbuf, Ubuf, Vbuf);
  k5_mfma<<<dim3(8, 32), 256, 0, stream>>>(Zbuf, Ubuf, Vbuf, XpT, vt_out);
}